// Round 8
// baseline (2371.452 us; speedup 1.0000x reference)
//
#include <hip/hip_runtime.h>
#include <math.h>

// Problem dims
#define S_N   512
#define WL_N  100
#define E_N   200
#define OC_N  50
#define H_N   400

// ---------------------------------------------------------------------------
// K1: pooled[s][400] = conv_b + (1/L) * sum_{t<L} conv(emb[x])  via prefix sums
// 8 sentences per block: conv weights streamed ONCE per block (8 FMA/weight),
// cutting weight traffic 8x (4.9 GB -> 614 MB). Wave-cooperative conv.
// Block 0 also zeroes the GRU hbuf (removes a memset dispatch).
// ---------------------------------------------------------------------------
template<int K>
__device__ inline void conv_dot8(const float* __restrict__ wbase,
                                 const float (*Ap)[E_N][17], int lane,
                                 float* __restrict__ acc)
{
  constexpr int W = 2 * K + 1;
  constexpr int n = E_N * W;
  for (int idx = lane; idx < n; idx += 64) {
    int e = idx / W;
    int k = idx - e * W;
    float w = wbase[idx];
    #pragma unroll
    for (int ss = 0; ss < 8; ++ss)
      acc[ss] += w * Ap[ss][e][7 - K + k];
  }
}

__global__ __launch_bounds__(256, 1)
void pooled_kernel(const int* __restrict__ x, const float* __restrict__ emb,
                   const float* __restrict__ cw0, const float* __restrict__ cw1,
                   const float* __restrict__ cw2, const float* __restrict__ cw3,
                   const float* __restrict__ cw4, const float* __restrict__ cw5,
                   const float* __restrict__ cw6, const float* __restrict__ cw7,
                   const float* __restrict__ conv_b, float* __restrict__ pooled,
                   unsigned long long* __restrict__ hz)
{
  const int s0 = blockIdx.x * 8;
  const int tid = threadIdx.x;
  __shared__ int   xr[8][WL_N];
  __shared__ int   Ls[8];
  __shared__ float invLs[8];
  __shared__ float Ap[8][E_N][17];   // 108.8 KB

  if (blockIdx.x == 0)
    for (int l = tid; l < 1600; l += 256) hz[l] = 0ull;

  for (int l = tid; l < 8 * WL_N; l += 256)
    xr[l / WL_N][l % WL_N] = x[s0 * WL_N + l];
  __syncthreads();
  if (tid < 8) {
    int L = 0;
    for (int t = 0; t < WL_N; ++t) L += (xr[tid][t] != 0) ? 1 : 0;
    Ls[tid] = L;                       // guaranteed in [20,100]
    invLs[tid] = 1.f / (float)L;
  }
  __syncthreads();

  // prefix stage: thread e (<200) handles all 8 sentences serially.
  if (tid < E_N) {
    const int e = tid;
    for (int ss = 0; ss < 8; ++ss) {
      const int L = Ls[ss];
      const int Lp7 = (L + 7 < WL_N) ? (L + 7) : WL_N;
      float P1 = 0, P2 = 0, P3 = 0, P4 = 0, P5 = 0, P6 = 0, P7 = 0;
      float acc = 0.f;
      // first 7 prefix values in named scalars (L>=20 -> never in A-window)
      #pragma unroll
      for (int tt = 0; tt < 7; ++tt) {
        acc += emb[(size_t)xr[ss][tt] * E_N + e];
        if (tt == 0) P1 = acc;  if (tt == 1) P2 = acc;  if (tt == 2) P3 = acc;
        if (tt == 3) P4 = acc;  if (tt == 4) P5 = acc;  if (tt == 5) P6 = acc;
        if (tt == 6) P7 = acc;
      }
      for (int t = 7; t < Lp7; ++t) {
        acc += emb[(size_t)xr[ss][t] * E_N + e];
        int rel = (t + 1) - (L - 7);
        if (rel >= 0 && rel < 15) Ap[ss][e][rel] = acc;   // P[L-7+rel]
      }
      const float accF = acc;   // P[Lp7] == P[100] whenever m>100 reachable
      #pragma unroll
      for (int dd = 0; dd < 15; ++dd) {
        int m = L - 7 + dd;
        float A = (m > WL_N) ? accF : Ap[ss][e][dd];
        float Bv = 0.f;
        if (dd == 8)  Bv = P1;  else if (dd == 9)  Bv = P2;
        else if (dd == 10) Bv = P3; else if (dd == 11) Bv = P4;
        else if (dd == 12) Bv = P5; else if (dd == 13) Bv = P6;
        else if (dd == 14) Bv = P7;
        Ap[ss][e][dd] = A - Bv;   // sum_{t<L} in[e][t+d], d = dd-7
      }
    }
  }
  __syncthreads();

  // conv stage: one (K,oc) pair per wave iteration; 8 sentences per weight.
  const int wv = tid >> 6, lane = tid & 63;
  for (int p = wv; p < 400; p += 4) {
    const int K = p / 50, oc = p % 50;
    float acc[8] = {};
    switch (K) {
      case 0: conv_dot8<0>(cw0 + (size_t)oc * 200,  Ap, lane, acc); break;
      case 1: conv_dot8<1>(cw1 + (size_t)oc * 600,  Ap, lane, acc); break;
      case 2: conv_dot8<2>(cw2 + (size_t)oc * 1000, Ap, lane, acc); break;
      case 3: conv_dot8<3>(cw3 + (size_t)oc * 1400, Ap, lane, acc); break;
      case 4: conv_dot8<4>(cw4 + (size_t)oc * 1800, Ap, lane, acc); break;
      case 5: conv_dot8<5>(cw5 + (size_t)oc * 2200, Ap, lane, acc); break;
      case 6: conv_dot8<6>(cw6 + (size_t)oc * 2600, Ap, lane, acc); break;
      case 7: conv_dot8<7>(cw7 + (size_t)oc * 3000, Ap, lane, acc); break;
    }
    #pragma unroll
    for (int ss = 0; ss < 8; ++ss) {
      float a = acc[ss];
      a += __shfl_xor(a, 1);  a += __shfl_xor(a, 2);  a += __shfl_xor(a, 4);
      a += __shfl_xor(a, 8);  a += __shfl_xor(a, 16); a += __shfl_xor(a, 32);
      acc[ss] = a;
    }
    if (lane == 0) {
      #pragma unroll
      for (int ss = 0; ss < 8; ++ss)
        pooled[(size_t)(s0 + ss) * 400 + p] = conv_b[p] + acc[ss] * invLs[ss];
    }
  }
}

// ---------------------------------------------------------------------------
// K2: merged gi GEMM: gi[512][2400] = pooled @ [w_ih_f; w_ih_b]^T + biases
// ---------------------------------------------------------------------------
__global__ __launch_bounds__(256, 2)
void gemm_gi(const float* __restrict__ A,   // pooled [512][400]
             const float* __restrict__ wf, const float* __restrict__ bf,
             const float* __restrict__ wb, const float* __restrict__ bb,
             float* __restrict__ C)         // gi [512][2400]
{
  __shared__ float As[16][65];
  __shared__ float Bs[16][65];
  const int bm = blockIdx.y * 64, bn = blockIdx.x * 64;
  const int tid = threadIdx.x;
  const int tr = (tid / 16) * 4, tc = (tid % 16) * 4;
  float acc[4][4] = {};
  for (int k0 = 0; k0 < 400; k0 += 16) {
    for (int l = tid; l < 64 * 16; l += 256) {
      int r = l / 16, c = l % 16;
      As[c][r] = A[(size_t)(bm + r) * 400 + k0 + c];
    }
    for (int l = tid; l < 64 * 16; l += 256) {
      int r = l / 16, c = l % 16;
      int gcol = bn + r;
      float v = 0.f;
      if (gcol < 1200)      v = wf[(size_t)gcol * 400 + k0 + c];
      else if (gcol < 2400) v = wb[(size_t)(gcol - 1200) * 400 + k0 + c];
      Bs[c][r] = v;
    }
    __syncthreads();
    #pragma unroll
    for (int kk = 0; kk < 16; ++kk) {
      float a[4], b[4];
      #pragma unroll
      for (int u = 0; u < 4; ++u) { a[u] = As[kk][tr + u]; b[u] = Bs[kk][tc + u]; }
      #pragma unroll
      for (int u = 0; u < 4; ++u)
        #pragma unroll
        for (int v = 0; v < 4; ++v) acc[u][v] += a[u] * b[v];
    }
    __syncthreads();
  }
  for (int u = 0; u < 4; ++u) {
    int r = bm + tr + u;
    for (int v = 0; v < 4; ++v) {
      int c = bn + tc + v; if (c >= 2400) continue;
      float bias = (c < 1200) ? bf[c] : bb[c - 1200];
      C[(size_t)r * 2400 + c] = acc[u][v] + bias;
    }
  }
}

// ---------------------------------------------------------------------------
// 32x32-tile GEMM: C[M,N] = A[M,K] @ B[N,K]^T + bias[N] (optional tanh).
// ---------------------------------------------------------------------------
template<int TAG>
__global__ __launch_bounds__(256, 4)
void gemm32(const float* __restrict__ A, int lda,
            const float* __restrict__ Bw, int ldb,
            const float* __restrict__ bias,
            float* __restrict__ C, int ldc,
            int M, int N, int K, int act)
{
  __shared__ float As[32][33];
  __shared__ float Bs[32][33];
  const int bm = blockIdx.y * 32, bn = blockIdx.x * 32;
  const int tid = threadIdx.x;
  const int tr = (tid >> 4) * 2, tc = (tid & 15) * 2;
  float acc[2][2] = {};
  for (int k0 = 0; k0 < K; k0 += 32) {
    #pragma unroll
    for (int p = 0; p < 4; ++p) {
      int l = tid + p * 256;
      int r = l >> 5, c = l & 31;
      As[c][r] = (bm + r < M) ? A[(size_t)(bm + r) * lda + k0 + c] : 0.f;
      Bs[c][r] = (bn + r < N) ? Bw[(size_t)(bn + r) * ldb + k0 + c] : 0.f;
    }
    __syncthreads();
    #pragma unroll
    for (int kk = 0; kk < 32; ++kk) {
      float a0 = As[kk][tr], a1 = As[kk][tr + 1];
      float b0 = Bs[kk][tc], b1 = Bs[kk][tc + 1];
      acc[0][0] += a0 * b0; acc[0][1] += a0 * b1;
      acc[1][0] += a1 * b0; acc[1][1] += a1 * b1;
    }
    __syncthreads();
  }
  #pragma unroll
  for (int u = 0; u < 2; ++u) {
    int r = bm + tr + u; if (r >= M) continue;
    #pragma unroll
    for (int v = 0; v < 2; ++v) {
      int c = bn + tc + v; if (c >= N) continue;
      float xv = acc[u][v] + (bias ? bias[c] : 0.f);
      if (act == 1) xv = tanhf(xv);
      C[(size_t)r * ldc + c] = xv;
    }
  }
}

// ---------------------------------------------------------------------------
// K3: bidirectional GRU scan, 25 blocks x 256 threads per direction.
// Round-3 tagged-data protocol, MERGED-WAVE structure: each wave owns 4
// h-indices end-to-end (dot -> 16-lane reduce -> lane cc==0 computes h and
// stores). Order: poll -> bar[A] -> dot (+hprev read) -> bar[B] ->
// h-compute+store (overlaps other waves' poll of t+1). bar[B] guarantees all
// hs reads complete before any wave stages t+1 into hs. Mean folded in.
// ---------------------------------------------------------------------------
#define GRU_NB 25
#define GRU_CHUNK 16
#define LDA64(p) __hip_atomic_load((p), __ATOMIC_RELAXED, __HIP_MEMORY_SCOPE_AGENT)
__global__ __launch_bounds__(256, 1)
void gru_scan_kernel(const float* __restrict__ gi,  // [512][2400] f|b
                     const float* __restrict__ whh_f, const float* __restrict__ bhh_f,
                     const float* __restrict__ whh_b, const float* __restrict__ bhh_b,
                     float* __restrict__ enc,                  // [512][800]
                     float* __restrict__ mean,                 // [800]
                     unsigned long long* __restrict__ hbuf)    // [2 dirs][2][400]
{
  const int tid = threadIdx.x;
  const int dir = blockIdx.x / GRU_NB;
  const int b   = blockIdx.x % GRU_NB;
  const float* whh = dir ? whh_b : whh_f;
  const float* bhh = dir ? bhh_b : bhh_f;
  unsigned long long* hb = hbuf + (size_t)dir * 800;
  const int i0 = b * GRU_CHUNK;

  __shared__ float wl[48][400];   // 76.8 KB
  __shared__ float hs[400];

  for (int l = tid; l < 48 * 400; l += 256) {
    int lr = l / 400, c = l % 400;
    int g = lr / GRU_CHUNK, ii = lr % GRU_CHUNK;
    wl[lr][c] = whh[(size_t)(g * 400 + i0 + ii) * 400 + c];
  }

  const int hi = tid >> 4;   // 0..15: h-index within our chunk
  const int cc = tid & 15;   // 0..15: column chunk
  const int c0 = cc * 25;

  // lane-personal h state (meaningful on cc==0 lanes)
  float blr = 0.f, blz = 0.f, bln = 0.f, msum = 0.f;
  float g0r = 0.f, g0z = 0.f, g0n = 0.f;   // gi row t
  float g1r = 0.f, g1z = 0.f, g1n = 0.f;   // gi row t+1
  if (cc == 0) {
    blr = bhh[i0 + hi];
    blz = bhh[400 + i0 + hi];
    bln = bhh[800 + i0 + hi];
    int t0 = dir ? 511 : 0;
    const float* g = gi + (size_t)t0 * 2400 + dir * 1200 + i0 + hi;
    g0r = g[0]; g0z = g[400]; g0n = g[800];
    int t1 = dir ? 510 : 1;
    g = gi + (size_t)t1 * 2400 + dir * 1200 + i0 + hi;
    g1r = g[0]; g1z = g[400]; g1n = g[800];
  }
  __syncthreads();

  const bool two = (tid < 144);     // covers word tid+256

  for (int t = 0; t < 512; ++t) {
    const int t_in = dir ? (511 - t) : t;
    // ---- all waves: 2-deep pipelined tag poll + stage to hs ----
    {
      const unsigned long long* src = hb + (t & 1) * 400;
      const unsigned want = (unsigned)t;
      unsigned long long a0, a1 = 0, b0, b1 = 0, r0, r1 = 0;
      a0 = LDA64(src + tid); if (two) a1 = LDA64(src + tid + 256);
      b0 = LDA64(src + tid); if (two) b1 = LDA64(src + tid + 256);
      for (;;) {
        bool ok = ((unsigned)(a0 >> 32) == want) && (!two || ((unsigned)(a1 >> 32) == want));
        if (__all(ok)) { r0 = a0; r1 = a1; break; }
        a0 = LDA64(src + tid); if (two) a1 = LDA64(src + tid + 256);
        ok = ((unsigned)(b0 >> 32) == want) && (!two || ((unsigned)(b1 >> 32) == want));
        if (__all(ok)) { r0 = b0; r1 = b1; break; }
        b0 = LDA64(src + tid); if (two) b1 = LDA64(src + tid + 256);
      }
      hs[tid] = __uint_as_float((unsigned)r0);
      if (two) hs[tid + 256] = __uint_as_float((unsigned)r1);
    }
    __syncthreads();   // [A] hs ready

    // ---- dot: 3 gates x 25-column slice; in-wave 16-lane reduce ----
    float a0 = 0.f, a1 = 0.f, a2 = 0.f;
    #pragma unroll
    for (int j = 0; j < 25; ++j) {
      float hv = hs[c0 + j];
      a0 += wl[hi][c0 + j] * hv;
      a1 += wl[16 + hi][c0 + j] * hv;
      a2 += wl[32 + hi][c0 + j] * hv;
    }
    #pragma unroll
    for (int m = 1; m <= 8; m <<= 1) {
      a0 += __shfl_xor(a0, m);
      a1 += __shfl_xor(a1, m);
      a2 += __shfl_xor(a2, m);
    }
    float hprev = 0.f;
    if (cc == 0) hprev = hs[i0 + hi];   // read before [B]
    __syncthreads();   // [B] all hs reads done -> safe to poll/stage t+1

    // ---- cc==0 lanes: h compute + stores (overlaps others' next poll) ----
    if (cc == 0) {
      float r = 1.f / (1.f + expf(-(g0r + a0 + blr)));
      float z = 1.f / (1.f + expf(-(g0z + a1 + blz)));
      float n = tanhf(g0n + r * (a2 + bln));
      float hn = (1.f - z) * n + z * hprev;
      msum += hn;
      unsigned long long pk =
          ((unsigned long long)(unsigned)(t + 1) << 32) |
          (unsigned long long)__float_as_uint(hn);
      __hip_atomic_store(hb + ((t + 1) & 1) * 400 + i0 + hi, pk,
                         __ATOMIC_RELAXED, __HIP_MEMORY_SCOPE_AGENT);
      enc[(size_t)t_in * 800 + dir * 400 + i0 + hi] = hn;
      // rotate gi pipeline; prefetch step t+2
      g0r = g1r; g0z = g1z; g0n = g1n;
      int t2 = t + 2; if (t2 > 511) t2 = 511;
      int tn2 = dir ? (511 - t2) : t2;
      const float* g = gi + (size_t)tn2 * 2400 + dir * 1200 + i0 + hi;
      g1r = g[0]; g1z = g[400]; g1n = g[800];
    }
  }
  if (cc == 0)
    mean[dir * 400 + i0 + hi] = msum * (1.f / 512.f);
}

// ---------------------------------------------------------------------------
// K6: decoder. Prologue computes doc = tanh(W_doc@mean + b_doc) and
// dt = W_d1[:,1200:1600]@doc in-kernel (replaces doc/docterm kernels).
// Main: parallel segment passes (q constant between selections, <=nos sels).
// pre1 already includes b_d1 (gemm bias).
// ---------------------------------------------------------------------------
__global__ __launch_bounds__(1024, 1)
void decoder_kernel(const float* __restrict__ pre1,   // [512][100] (+b_d1)
                    const float* __restrict__ Qb,     // [512][100]
                    const float* __restrict__ mean,   // [800]
                    const float* __restrict__ W_doc,  // [400][800]
                    const float* __restrict__ b_doc,  // [400]
                    const float* __restrict__ W_d1,   // [100][1600]
                    const float* __restrict__ W_d2,   // [100]
                    const float* __restrict__ b_d2,   // [1]
                    const int* __restrict__ nos_p,
                    float* __restrict__ out)          // [513]: logp, sels
{
  const int tid = threadIdx.x;
  const int row = tid >> 1;
  const int half = tid & 1;
  __shared__ float mean_s[800];
  __shared__ float doc_s[400];
  __shared__ float dt_s[100];
  __shared__ float q[100];
  __shared__ float w2s[100];
  __shared__ int   selfl[512];
  __shared__ int   firstpos;
  __shared__ float red[16];

  if (tid < 800) mean_s[tid] = mean[tid];
  if (tid < 100) { q[tid] = 0.f; w2s[tid] = W_d2[tid]; }
  if (tid < 512) selfl[tid] = 0;
  __syncthreads();

  const int w = tid >> 6, l = tid & 63;
  // doc: 16 waves x 25 rows, 64-lane cooperative dot over 800
  for (int rr = 0; rr < 25; ++rr) {
    int r = w * 25 + rr;
    float s = 0.f;
    for (int k = l; k < 800; k += 64) s += W_doc[(size_t)r * 800 + k] * mean_s[k];
    s += __shfl_xor(s, 1);  s += __shfl_xor(s, 2);  s += __shfl_xor(s, 4);
    s += __shfl_xor(s, 8);  s += __shfl_xor(s, 16); s += __shfl_xor(s, 32);
    if (l == 0) doc_s[r] = tanhf(s + b_doc[r]);
  }
  __syncthreads();
  // dt: rows strided over 16 waves
  for (int r = w; r < 100; r += 16) {
    float s = 0.f;
    for (int k = l; k < 400; k += 64) s += W_d1[(size_t)r * 1600 + 1200 + k] * doc_s[k];
    s += __shfl_xor(s, 1);  s += __shfl_xor(s, 2);  s += __shfl_xor(s, 4);
    s += __shfl_xor(s, 8);  s += __shfl_xor(s, 16); s += __shfl_xor(s, 32);
    if (l == 0) dt_s[r] = s;
  }
  __syncthreads();

  float pr[50];
  #pragma unroll
  for (int k = 0; k < 50; ++k)
    pr[k] = pre1[(size_t)row * 100 + half * 50 + k] + dt_s[half * 50 + k];
  const float bd2 = b_d2[0];
  const int nos = nos_p[0];
  int count = 0, seg = 0;
  float logp_part = 0.f;
  __syncthreads();

  for (int pass = 0; pass < 600 && seg < 512; ++pass) {
    const bool allowed = (nos <= 0) || (count < nos);
    if (tid == 0) firstpos = 512;
    float acc = 0.f;
    #pragma unroll
    for (int k = 0; k < 50; ++k)
      acc += w2s[half * 50 + k] * tanhf(pr[k] + q[half * 50 + k]);
    acc += __shfl_xor(acc, 1);     // combine the two halves of this row
    const float sv = acc + bd2;    // logit; p>0.5 <=> sv>0
    __syncthreads();
    if (allowed && half == 0 && row >= seg && sv > 0.f)
      atomicMin(&firstpos, row);
    __syncthreads();
    const int fp = allowed ? firstpos : 512;
    const int lim = (fp < 512) ? fp : 511;
    if (half == 0 && row >= seg && row <= lim) {
      float p = 1.f / (1.f + expf(-sv));
      float term = (row == fp) ? p : (1.f - p);
      logp_part += logf(term * 0.99999f + 5e-6f);
      if (row == fp) selfl[row] = 1;
    }
    if (fp < 512) {
      if (tid < 100) q[tid] += Qb[(size_t)fp * 100 + tid];
      count += 1;
      seg = fp + 1;
    } else {
      seg = 512;
    }
    __syncthreads();
  }

  float v = logp_part;
  v += __shfl_xor(v, 1);  v += __shfl_xor(v, 2);  v += __shfl_xor(v, 4);
  v += __shfl_xor(v, 8);  v += __shfl_xor(v, 16); v += __shfl_xor(v, 32);
  if ((tid & 63) == 0) red[tid >> 6] = v;
  __syncthreads();
  if (tid == 0) {
    float s = 0.f;
    #pragma unroll
    for (int ww = 0; ww < 16; ++ww) s += red[ww];
    out[0] = s;
  }
  if (half == 0) out[1 + row] = (float)selfl[row];
}

// ---------------------------------------------------------------------------
// Launcher — 7 dispatches
// ---------------------------------------------------------------------------
extern "C" void kernel_launch(void* const* d_in, const int* in_sizes, int n_in,
                              void* d_out, int out_size, void* d_ws, size_t ws_size,
                              hipStream_t stream) {
  const int*   x      = (const int*)  d_in[0];
  const int*   nos    = (const int*)  d_in[1];
  const float* emb    = (const float*)d_in[2];
  const float* cw[8];
  for (int k = 0; k < 8; ++k) cw[k] = (const float*)d_in[3 + k];
  const float* conv_b = (const float*)d_in[11];
  const float* w_ih_f = (const float*)d_in[12];
  const float* w_hh_f = (const float*)d_in[13];
  const float* b_ih_f = (const float*)d_in[14];
  const float* b_hh_f = (const float*)d_in[15];
  const float* w_ih_b = (const float*)d_in[16];
  const float* w_hh_b = (const float*)d_in[17];
  const float* b_ih_b = (const float*)d_in[18];
  const float* b_hh_b = (const float*)d_in[19];
  const float* W_doc  = (const float*)d_in[20];
  const float* b_doc  = (const float*)d_in[21];
  const float* W_d1   = (const float*)d_in[22];
  const float* b_d1   = (const float*)d_in[23];
  const float* W_d2   = (const float*)d_in[24];
  const float* b_d2   = (const float*)d_in[25];
  const float* W_r    = (const float*)d_in[26];
  const float* b_r    = (const float*)d_in[27];

  float* ws = (float*)d_ws;
  const size_t OFF_POOLED  = 0;         // 512*400
  const size_t OFF_GI      = 204800;    // 512*2400 (reused as Qbuf later)
  const size_t OFF_ENC     = 1433600;   // 512*800
  const size_t OFF_R       = 1843200;   // 512*400 (hbuf aliases this, dead until R-gemm)
  const size_t OFF_PRE1    = 2048000;   // 512*100
  const size_t OFF_MEAN    = 2099200;   // 800
  float* pooled  = ws + OFF_POOLED;
  float* gi      = ws + OFF_GI;
  float* enc     = ws + OFF_ENC;
  float* Rbuf    = ws + OFF_R;
  float* pre1    = ws + OFF_PRE1;
  float* mean    = ws + OFF_MEAN;
  float* Qbuf    = ws + OFF_GI;     // gi dead after GRU; reuse for Q
  // hbuf aliases the Rbuf region (dead until gemm32<1> runs, after GRU):
  unsigned long long* hbuf = (unsigned long long*)(ws + OFF_R);

  // K1: pooled (+ zero hbuf in block 0)
  pooled_kernel<<<64, 256, 0, stream>>>(x, emb, cw[0], cw[1], cw[2], cw[3],
                                        cw[4], cw[5], cw[6], cw[7], conv_b,
                                        pooled, hbuf);

  // K2: gi = pooled @ [w_ih_f; w_ih_b]^T + bias  -> [512][2400]
  gemm_gi<<<dim3(38, 8), 256, 0, stream>>>(pooled, w_ih_f, b_ih_f, w_ih_b, b_ih_b, gi);

  // K3: GRU scan (writes enc + mean)
  gru_scan_kernel<<<2 * GRU_NB, 256, 0, stream>>>(gi, w_hh_f, b_hh_f, w_hh_b, b_hh_b,
                                                  enc, mean, hbuf);

  // R = tanh(enc @ W_r^T + b_r)  [512][400]
  gemm32<1><<<dim3(13, 16), 256, 0, stream>>>(enc, 800, W_r, 800, b_r,
                                              Rbuf, 400, 512, 400, 800, 1);
  // Q = R @ W_d1[:,800:1200]^T  [512][100]
  gemm32<2><<<dim3(4, 16), 256, 0, stream>>>(Rbuf, 400, W_d1 + 800, 1600, nullptr,
                                             Qbuf, 100, 512, 100, 400, 0);
  // pre1 = enc @ W_d1[:, :800]^T + b_d1  [512][100] (doc term added in decoder)
  gemm32<3><<<dim3(4, 16), 256, 0, stream>>>(enc, 800, W_d1, 1600, b_d1,
                                             pre1, 100, 512, 100, 800, 0);

  // K6: decoder (includes doc + dt prologue)
  decoder_kernel<<<1, 1024, 0, stream>>>(pre1, Qbuf, mean, W_doc, b_doc, W_d1,
                                         W_d2, b_d2, nos, (float*)d_out);
}